// Round 12
// baseline (300.585 us; speedup 1.0000x reference)
//
#include <hip/hip_runtime.h>
#include <stdint.h>

#define BATCH   32768
#define NSUP    256
#define NSUB    1024
#define LATENT  512
#define NOUT    200
#define SUP_OFF ((size_t)BATCH * NOUT)  // sup_out offset in d_out
#define TOTAL_B 3088                    // k_main grid: 16 sup + 3072 gemm

typedef unsigned short u16;
typedef __attribute__((ext_vector_type(8))) __bf16 bf16x8;
typedef __attribute__((ext_vector_type(4))) float  floatx4;

typedef const __attribute__((address_space(1))) void* gptr_t;
typedef __attribute__((address_space(3))) void* sptr_t;

__device__ __forceinline__ void gload16(const void* g, void* l) {
  __builtin_amdgcn_global_load_lds((gptr_t)g, (sptr_t)l, 16, 0, 0);
}

__device__ __forceinline__ floatx4 mfma_bf16(bf16x8 a, bf16x8 b, floatx4 c) {
  return __builtin_amdgcn_mfma_f32_16x16x32_bf16(a, b, c, 0, 0, 0);
}

__device__ __forceinline__ u16 f2bf(float f) {
  unsigned int u = __float_as_uint(f);
  u += 0x7FFFu + ((u >> 16) & 1u);   // RNE; inputs finite
  return (u16)(u >> 16);
}

// =============== k_setup2: R6 verbatim (verified in the 230.6 config).
// bx [0,256)    : Mt[o][k] = -2 sum_j W[o,j] P[j,k]  (s_load W, coalesced P)
// bx [256,8768) : conversions, contiguous rows: x->xb/xxb, sup->sups/xxsup, sub->subs/yys
// bx [8768,8905): init 35072 min-slots; bx 8905: zero out4 + done
__global__ __launch_bounds__(256) void k_setup2(const float* __restrict__ x,
    const float* __restrict__ sup, const float* __restrict__ sub,
    const float* __restrict__ W1, const float* __restrict__ W2,
    u16* __restrict__ xb, float* __restrict__ xxb,
    u16* __restrict__ sups, u16* __restrict__ subs,
    float* __restrict__ xxsup, float* __restrict__ yys,
    u16* __restrict__ Mt, unsigned int* __restrict__ minbuf,
    float* __restrict__ out4, unsigned int* __restrict__ done) {
  int bx = blockIdx.x, t = threadIdx.x;
  if (bx < 256) {
    int og = bx >> 2, kq = bx & 3;
    int o0 = og * 8;
    int kk = t & 127, oh = t >> 7;     // oh uniform within each wave
    int k  = kq * 128 + kk;
    if (o0 >= 400) {
#pragma unroll
      for (int oo = 0; oo < 4; oo++) Mt[(size_t)(o0 + oh * 4 + oo) * LATENT + k] = 0;
      return;
    }
    const float* P; const float* W; int n, ow;
    if (o0 < 200) { P = sup; W = W1; n = NSUP;  ow = o0; }
    else          { P = sub; W = W2; n = NSUB;  ow = o0 - 200; }
    const float* W0 = W + (size_t)(ow + oh * 4) * n;
    float a[4] = {};
    for (int j = 0; j < n; j += 16) {
      float pv[16];
#pragma unroll
      for (int u = 0; u < 16; u++) pv[u] = P[(size_t)(j + u) * LATENT + k];
#pragma unroll
      for (int oo = 0; oo < 4; oo++) {
        const float* Wr = W0 + (size_t)oo * n + j;   // wave-uniform -> s_load
#pragma unroll
        for (int u = 0; u < 16; u++) a[oo] += pv[u] * Wr[u];
      }
    }
#pragma unroll
    for (int oo = 0; oo < 4; oo++)
      Mt[(size_t)(o0 + oh * 4 + oo) * LATENT + k] = f2bf(-2.f * a[oo]);
    return;
  }
  if (bx >= 8768) {
    if (bx == 8905) {
      if (t < 4) out4[t] = 0.f;
      if (t == 4) *done = 0u;
      return;
    }
    int i = (bx - 8768) * 256 + t;
    if (i < BATCH + NSUP + 2 * NSUB) minbuf[i] = 0x7F800000u;
    return;
  }
  // ---- conversions + row norms (contiguous mapping)
  int wave = t >> 6, lane = t & 63;
  int row  = (bx - 256) * 4 + wave;
  const float* src; u16* dst; float* nrm;
  if (row < BATCH) {
    src = x + (size_t)row * LATENT; dst = xb + (size_t)row * LATENT; nrm = xxb + row;
  } else if (row < BATCH + NSUP) {
    int r = row - BATCH;
    src = sup + (size_t)r * LATENT; dst = sups + (size_t)r * LATENT; nrm = xxsup + r;
  } else {
    int r = row - BATCH - NSUP;
    src = sub + (size_t)r * LATENT; dst = subs + (size_t)r * LATENT; nrm = yys + r;
  }
  const float* s = src + lane * 8;
  float4 v0 = ((const float4*)s)[0];
  float4 v1 = ((const float4*)s)[1];
  float ss = v0.x*v0.x + v0.y*v0.y + v0.z*v0.z + v0.w*v0.w
           + v1.x*v1.x + v1.y*v1.y + v1.z*v1.z + v1.w*v1.w;
  uint4 o;
  o.x = (unsigned)f2bf(v0.x) | ((unsigned)f2bf(v0.y) << 16);
  o.y = (unsigned)f2bf(v0.z) | ((unsigned)f2bf(v0.w) << 16);
  o.z = (unsigned)f2bf(v1.x) | ((unsigned)f2bf(v1.y) << 16);
  o.w = (unsigned)f2bf(v1.z) | ((unsigned)f2bf(v1.w) << 16);
  *((uint4*)(dst + lane * 8)) = o;
  for (int off = 32; off; off >>= 1) ss += __shfl_down(ss, off);
  if (lane == 0) *nrm = ss;
}

// =============== k_w: sc/cc from precomputed norms (verified fast)
__global__ __launch_bounds__(256) void k_w(const float* __restrict__ W1,
    const float* __restrict__ b1, const float* __restrict__ W2,
    const float* __restrict__ b2, const float* __restrict__ xxsup,
    const float* __restrict__ yys, float* __restrict__ sc, float* __restrict__ cc) {
  int wave = threadIdx.x >> 6, lane = threadIdx.x & 63;
  int o = blockIdx.x * 4 + wave;
  if (o >= 400) return;
  int n; const float* Wr; const float* yy;
  if (o < 200) { n = NSUP; Wr = W1 + (size_t)o * NSUP; yy = xxsup; }
  else         { n = NSUB; Wr = W2 + (size_t)(o - 200) * NSUB; yy = yys; }
  float s = 0.f, c = 0.f;
  for (int j = lane; j < n; j += 64) { float w = Wr[j]; s += w; c += w * yy[j]; }
  for (int off = 32; off; off >>= 1) { s += __shfl_down(s, off); c += __shfl_down(c, off); }
  if (lane == 0) { sc[o] = s; cc[o] = c + ((o < 200) ? b1[o] : b2[o - 200]); }
}

// =============== k_main: R6-verified BK=64 K-loop (84 µs, 0 conflicts) + fused
// finisher (R8 mechanism: vmcnt-only wait on own LLC-coherent atomics, NO fence).
// launch_bounds(256,5): LDS 32KB x 5 = 160KB exact -> 5 blocks/CU.
// bx [0,16): sup x sub tiles first; bx [16,3088): x-GEMM tiles, XCD-swizzled.
__global__ __launch_bounds__(256, 5) void k_main(const u16* __restrict__ xb,
    const u16* __restrict__ Bext, const float* __restrict__ xxb,
    const float* __restrict__ xxsup, const float* __restrict__ yys,
    const float* __restrict__ sc, const float* __restrict__ cc,
    const u16* __restrict__ sups, const u16* __restrict__ subs,
    float* __restrict__ out, float* __restrict__ out4,
    unsigned int* __restrict__ rowmin, unsigned int* __restrict__ colx,
    unsigned int* __restrict__ colsup, unsigned int* __restrict__ done) {
  __shared__ __align__(16) u16 lA[128 * 64];
  __shared__ __align__(16) u16 lB[128 * 64];
  int bx = blockIdx.x, t = threadIdx.x, wave = t >> 6, lane = t & 63;
  int l16 = lane & 15, qq = lane >> 4;
  int wm = (wave >> 1) * 64, wn = (wave & 1) * 64;

  const u16* Ab; const u16* Bb;
  int cb, isSup; size_t arow0;
  if (bx < 16) {
    cb = bx & 7; arow0 = (size_t)(bx >> 3) * 128; isSup = 1;
    Ab = sups + arow0 * LATENT; Bb = subs + (size_t)cb * 128 * LATENT;
  } else {
    int g = bx - 16;
    int xcd = g & 7, local = g >> 3;
    int rowt = xcd * 32 + local / 12;
    cb = local % 12;
    arow0 = (size_t)rowt * 128; isSup = 0;
    Ab = xb + arow0 * LATENT; Bb = Bext + (size_t)cb * 128 * LATENT;
  }

  floatx4 acc[4][4] = {};
  int sq = (lane & 7) ^ (lane >> 3);
  int soff[4]; u16 *dA[4], *dB[4];
#pragma unroll
  for (int i = 0; i < 4; i++) {
    int s = i * 256 + t;
    soff[i] = (s >> 3) * LATENT + sq * 8;
    int sbase = (i * 256 + wave * 64) * 8;
    dA[i] = lA + sbase; dB[i] = lB + sbase;
  }
  for (int k0 = 0; k0 < LATENT; k0 += 64) {
#pragma unroll
    for (int i = 0; i < 4; i++) gload16(Ab + soff[i] + k0, dA[i]);
#pragma unroll
    for (int i = 0; i < 4; i++) gload16(Bb + soff[i] + k0, dB[i]);
    __syncthreads();
#pragma unroll
    for (int ks = 0; ks < 2; ks++) {
      bf16x8 af[4], bvv[4];
      int sw = ((ks * 4 + qq) ^ (l16 & 7)) * 8;
#pragma unroll
      for (int f = 0; f < 4; f++) {
        af[f]  = *(const bf16x8*)(lA + (wm + f * 16 + l16) * 64 + sw);
        bvv[f] = *(const bf16x8*)(lB + (wn + f * 16 + l16) * 64 + sw);
      }
#pragma unroll
      for (int fm = 0; fm < 4; fm++)
#pragma unroll
        for (int fn = 0; fn < 4; fn++)
          acc[fm][fn] = mfma_bf16(af[fm], bvv[fn], acc[fm][fn]);
    }
    __syncthreads();
  }

  if (!isSup && cb < 4) {
    int colb = cb * 128 + wn + l16;
#pragma unroll
    for (int fn = 0; fn < 4; fn++) {
      int c = colb + fn * 16;
      if (c < 400) {
        float scv = sc[c], ccv = cc[c];
#pragma unroll
        for (int fm = 0; fm < 4; fm++)
#pragma unroll
          for (int r = 0; r < 4; r++) {
            size_t row = arow0 + wm + fm * 16 + qq * 4 + r;
            float v = acc[fm][fn][r] + xxb[row] * scv + ccv;
            size_t idx = (c < 200) ? (SUP_OFF + row * NOUT + c)
                                   : (row * NOUT + (c - 200));
            out[idx] = v;
          }
      }
    }
  } else {
    const float* xxsrc = (isSup ? xxsup : xxb) + arow0;
    const float* yyb   = yys + (isSup ? cb * 128 : (cb - 4) * 128);
    unsigned int* rmptr   = (isSup ? rowmin + BATCH : rowmin) + arow0;
    unsigned int* colatom = isSup ? (colsup + cb * 128) : (colx + (cb - 4) * 128);
    int colo = wn + l16;
    float yv[4];
#pragma unroll
    for (int fn = 0; fn < 4; fn++) yv[fn] = yyb[colo + fn * 16];
    float cmin[4] = {3.4e38f, 3.4e38f, 3.4e38f, 3.4e38f};
#pragma unroll
    for (int fm = 0; fm < 4; fm++) {
#pragma unroll
      for (int r = 0; r < 4; r++) {
        float xvv = xxsrc[wm + fm * 16 + qq * 4 + r];
        float rmin = 3.4e38f;
#pragma unroll
        for (int fn = 0; fn < 4; fn++) {
          float d = xvv - 2.0f * acc[fm][fn][r] + yv[fn];
          rmin = fminf(rmin, d);
          cmin[fn] = fminf(cmin[fn], d);
        }
        for (int off = 1; off < 16; off <<= 1) rmin = fminf(rmin, __shfl_xor(rmin, off));
        if (l16 == 0) atomicMin(rmptr + wm + fm * 16 + qq * 4 + r, __float_as_uint(rmin));
      }
    }
#pragma unroll
    for (int fn = 0; fn < 4; fn++) {
      float v = cmin[fn];
      v = fminf(v, __shfl_xor(v, 16));
      v = fminf(v, __shfl_xor(v, 32));
      if (qq == 0) atomicMin(colatom + colo + fn * 16, __float_as_uint(v));
    }
  }

  // ---- fused finisher (R8 mechanism: no fence; own atomics only need vmcnt)
  asm volatile("s_waitcnt vmcnt(0)" ::: "memory");
  __shared__ unsigned int lastf;
  if (t == 0) lastf = (atomicAdd(done, 1u) == (unsigned)(TOTAL_B - 1)) ? 1u : 0u;
  __syncthreads();
  if (lastf) {
    float* red = (float*)lA;
#pragma unroll 1
    for (int slot = 0; slot < 4; slot++) {
      const unsigned int* src; int n; float scale;
      if (slot == 0)      { src = colx;           n = NSUB;  scale = 1.f / NSUB;  }
      else if (slot == 1) { src = rowmin;         n = BATCH; scale = 1.f / BATCH; }
      else if (slot == 2) { src = rowmin + BATCH; n = NSUP;  scale = 1.f / NSUP;  }
      else                { src = colsup;         n = NSUB;  scale = 1.f / NSUB;  }
      float s = 0.f;
      for (int i = t; i < n; i += 256)
        s += __uint_as_float(__hip_atomic_load((unsigned int*)(src + i),
                             __ATOMIC_RELAXED, __HIP_MEMORY_SCOPE_AGENT));
      for (int off = 32; off; off >>= 1) s += __shfl_down(s, off);
      if ((t & 63) == 0) red[t >> 6] = s;
      __syncthreads();
      if (t == 0) out4[slot] = (red[0] + red[1] + red[2] + red[3]) * scale;
      __syncthreads();
    }
  }
}

extern "C" void kernel_launch(void* const* d_in, const int* in_sizes, int n_in,
                              void* d_out, int out_size, void* d_ws, size_t ws_size,
                              hipStream_t stream) {
  const float* x   = (const float*)d_in[0];
  const float* sup = (const float*)d_in[1];
  const float* sub = (const float*)d_in[2];
  const float* W1  = (const float*)d_in[3];
  const float* b1  = (const float*)d_in[4];
  const float* W2  = (const float*)d_in[5];
  const float* b2  = (const float*)d_in[6];
  float* out = (float*)d_out;

  char* p = (char*)d_ws;
  u16* Bext  = (u16*)p;            p += (size_t)(512 + NSUB) * LATENT * 2; // Mt(512) ++ subs(1024)
  u16* Mt    = Bext;
  u16* subs  = Bext + (size_t)512 * LATENT;
  u16* sups  = (u16*)p;            p += (size_t)NSUP * LATENT * 2;
  float* xxsup = (float*)p;        p += NSUP * 4;
  float* yys   = (float*)p;        p += NSUB * 4;
  float* sc    = (float*)p;        p += 512 * 4;
  float* cc    = (float*)p;        p += 512 * 4;
  unsigned int* rowmin = (unsigned int*)p; p += (size_t)(BATCH + NSUP) * 4;
  unsigned int* colx   = (unsigned int*)p; p += (size_t)NSUB * 4;
  unsigned int* colsup = (unsigned int*)p; p += (size_t)NSUB * 4;
  unsigned int* done   = (unsigned int*)p; p += 256;
  u16* xbuf    = (u16*)p;          p += (size_t)BATCH * LATENT * 2;   // 33.5 MB
  float* xxb   = (float*)p;        p += (size_t)BATCH * 4;

  float* out4 = out + 2 * SUP_OFF;

  hipLaunchKernelGGL(k_setup2, dim3(8906), dim3(256), 0, stream,
                     x, sup, sub, W1, W2, xbuf, xxb, sups, subs, xxsup, yys,
                     Mt, rowmin, out4, done);
  hipLaunchKernelGGL(k_w, dim3(100), dim3(256), 0, stream,
                     W1, b1, W2, b2, xxsup, yys, sc, cc);
  hipLaunchKernelGGL(k_main, dim3(TOTAL_B), dim3(256), 0, stream,
                     xbuf, Bext, xxb, xxsup, yys, sc, cc, sups, subs,
                     out, out4, rowmin, colx, colsup, done);
}

// Round 13
// 261.863 us; speedup vs baseline: 1.1479x; 1.1479x over previous
//
#include <hip/hip_runtime.h>
#include <stdint.h>

#define BATCH   32768
#define NSUP    256
#define NSUB    1024
#define LATENT  512
#define NOUT    200
#define SUP_OFF ((size_t)BATCH * NOUT)  // sup_out offset in d_out

typedef unsigned short u16;
typedef __attribute__((ext_vector_type(8))) __bf16 bf16x8;
typedef __attribute__((ext_vector_type(4))) float  floatx4;

typedef const __attribute__((address_space(1))) void* gptr_t;
typedef __attribute__((address_space(3))) void* sptr_t;

__device__ __forceinline__ void gload16(const void* g, void* l) {
  __builtin_amdgcn_global_load_lds((gptr_t)g, (sptr_t)l, 16, 0, 0);
}

__device__ __forceinline__ floatx4 mfma_bf16(bf16x8 a, bf16x8 b, floatx4 c) {
  return __builtin_amdgcn_mfma_f32_16x16x32_bf16(a, b, c, 0, 0, 0);
}

__device__ __forceinline__ u16 f2bf(float f) {
  unsigned int u = __float_as_uint(f);
  u += 0x7FFFu + ((u >> 16) & 1u);   // RNE; inputs finite
  return (u16)(u >> 16);
}

// =============== setup2: Mt build (s_load W path, no LDS) + conversions + inits.
// bx [0,256)    : Mt[o][k] = -2 sum_j W[o,j] P[j,k]; block = (o-group of 8, k-quarter)
//                 W reads are wave-uniform -> scalar loads; P reads coalesced vector.
// bx [256,8768) : conversions, row = (bx-256)*4+wave: x->xb/xxb, sup->sups/xxsup,
//                 sub->subs/yys
// bx [8768,8905): init 35072 min-slots; bx 8905: zero out4
__global__ __launch_bounds__(256) void k_setup2(const float* __restrict__ x,
    const float* __restrict__ sup, const float* __restrict__ sub,
    const float* __restrict__ W1, const float* __restrict__ W2,
    u16* __restrict__ xb, float* __restrict__ xxb,
    u16* __restrict__ sups, u16* __restrict__ subs,
    float* __restrict__ xxsup, float* __restrict__ yys,
    u16* __restrict__ Mt, unsigned int* __restrict__ minbuf,
    float* __restrict__ out4) {
  int bx = blockIdx.x, t = threadIdx.x;
  if (bx < 256) {
    int og = bx >> 2, kq = bx & 3;
    int o0 = og * 8;
    int kk = t & 127, oh = t >> 7;     // oh uniform within each wave
    int k  = kq * 128 + kk;
    if (o0 >= 400) {
#pragma unroll
      for (int oo = 0; oo < 4; oo++) Mt[(size_t)(o0 + oh * 4 + oo) * LATENT + k] = 0;
      return;
    }
    const float* P; const float* W; int n, ow;
    if (o0 < 200) { P = sup; W = W1; n = NSUP;  ow = o0; }
    else          { P = sub; W = W2; n = NSUB;  ow = o0 - 200; }
    const float* W0 = W + (size_t)(ow + oh * 4) * n;
    float a[4] = {};
    for (int j = 0; j < n; j += 16) {
      float pv[16];
#pragma unroll
      for (int u = 0; u < 16; u++) pv[u] = P[(size_t)(j + u) * LATENT + k];
#pragma unroll
      for (int oo = 0; oo < 4; oo++) {
        const float* Wr = W0 + (size_t)oo * n + j;   // wave-uniform -> s_load
#pragma unroll
        for (int u = 0; u < 16; u++) a[oo] += pv[u] * Wr[u];
      }
    }
#pragma unroll
    for (int oo = 0; oo < 4; oo++)
      Mt[(size_t)(o0 + oh * 4 + oo) * LATENT + k] = f2bf(-2.f * a[oo]);
    return;
  }
  if (bx >= 8768) {
    if (bx == 8905) { if (t < 4) out4[t] = 0.f; return; }
    int i = (bx - 8768) * 256 + t;
    if (i < BATCH + NSUP + 2 * NSUB) minbuf[i] = 0x7F800000u;
    return;
  }
  // ---- conversions + row norms
  int row  = (bx - 256) * 4 + (t >> 6);
  int lane = t & 63;
  const float* src; u16* dst; float* nrm;
  if (row < BATCH) {
    src = x + (size_t)row * LATENT; dst = xb + (size_t)row * LATENT; nrm = xxb + row;
  } else if (row < BATCH + NSUP) {
    int r = row - BATCH;
    src = sup + (size_t)r * LATENT; dst = sups + (size_t)r * LATENT; nrm = xxsup + r;
  } else {
    int r = row - BATCH - NSUP;
    src = sub + (size_t)r * LATENT; dst = subs + (size_t)r * LATENT; nrm = yys + r;
  }
  const float* s = src + lane * 8;
  float4 v0 = ((const float4*)s)[0];
  float4 v1 = ((const float4*)s)[1];
  float ss = v0.x*v0.x + v0.y*v0.y + v0.z*v0.z + v0.w*v0.w
           + v1.x*v1.x + v1.y*v1.y + v1.z*v1.z + v1.w*v1.w;
  uint4 o;
  o.x = (unsigned)f2bf(v0.x) | ((unsigned)f2bf(v0.y) << 16);
  o.y = (unsigned)f2bf(v0.z) | ((unsigned)f2bf(v0.w) << 16);
  o.z = (unsigned)f2bf(v1.x) | ((unsigned)f2bf(v1.y) << 16);
  o.w = (unsigned)f2bf(v1.z) | ((unsigned)f2bf(v1.w) << 16);
  *((uint4*)(dst + lane * 8)) = o;
  for (int off = 32; off; off >>= 1) ss += __shfl_down(ss, off);
  if (lane == 0) *nrm = ss;
}

// =============== k_w: sc/cc per output (needs xxsup/yys -> after k_setup2)
__global__ __launch_bounds__(256) void k_w(const float* __restrict__ W1,
    const float* __restrict__ b1, const float* __restrict__ W2,
    const float* __restrict__ b2, const float* __restrict__ xxsup,
    const float* __restrict__ yys, float* __restrict__ sc, float* __restrict__ cc) {
  int wave = threadIdx.x >> 6, lane = threadIdx.x & 63;
  int o = blockIdx.x * 4 + wave;
  if (o >= 400) return;
  int n; const float* Wr; const float* yy;
  if (o < 200) { n = NSUP; Wr = W1 + (size_t)o * NSUP; yy = xxsup; }
  else         { n = NSUB; Wr = W2 + (size_t)(o - 200) * NSUB; yy = yys; }
  float s = 0.f, c = 0.f;
  for (int j = lane; j < n; j += 64) { float w = Wr[j]; s += w; c += w * yy[j]; }
  for (int off = 32; off; off >>= 1) { s += __shfl_down(s, off); c += __shfl_down(c, off); }
  if (lane == 0) { sc[o] = s; cc[o] = c + ((o < 200) ? b1[o] : b2[o - 200]); }
}

// =============== main GEMM kernel: verified 128x128 K-loop (84 µs, 0 conflicts).
// bx [0,16)    : sup(256) x sub(1024) distance tiles FIRST (no serial tail).
// bx [16,3088) : x-GEMM tiles, XCD-swizzled (xcd owns 32 contiguous rowtiles x 12 panels).
// launch_bounds(256,4): 16 waves/CU residency (VGPR 64).
__global__ __launch_bounds__(256, 4) void k_main(const u16* __restrict__ xb,
    const u16* __restrict__ Bext, const float* __restrict__ xxb,
    const float* __restrict__ xxsup, const float* __restrict__ yys,
    const float* __restrict__ sc, const float* __restrict__ cc,
    const u16* __restrict__ sups, const u16* __restrict__ subs,
    float* __restrict__ out, unsigned int* __restrict__ rowmin,
    unsigned int* __restrict__ colx, unsigned int* __restrict__ colsup) {
  __shared__ __align__(16) u16 lA[128 * 64];
  __shared__ __align__(16) u16 lB[128 * 64];
  int bx = blockIdx.x, t = threadIdx.x, wave = t >> 6, lane = t & 63;
  int l16 = lane & 15, qq = lane >> 4;
  int wm = (wave >> 1) * 64, wn = (wave & 1) * 64;

  const u16* Ab; const u16* Bb;
  int cb, isSup; size_t arow0;
  if (bx < 16) {
    cb = bx & 7; arow0 = (size_t)(bx >> 3) * 128; isSup = 1;
    Ab = sups + arow0 * LATENT; Bb = subs + (size_t)cb * 128 * LATENT;
  } else {
    int g = bx - 16;
    int xcd = g & 7, local = g >> 3;
    int rowt = xcd * 32 + local / 12;
    cb = local % 12;
    arow0 = (size_t)rowt * 128; isSup = 0;
    Ab = xb + arow0 * LATENT; Bb = Bext + (size_t)cb * 128 * LATENT;
  }

  // ---- verified 128x128 K-loop (global_load_lds staging, pre-swizzled source)
  floatx4 acc[4][4] = {};
  int sq = (lane & 7) ^ (lane >> 3);
  int soff[4]; u16 *dA[4], *dB[4];
#pragma unroll
  for (int i = 0; i < 4; i++) {
    int s = i * 256 + t;
    soff[i] = (s >> 3) * LATENT + sq * 8;
    int sbase = (i * 256 + wave * 64) * 8;
    dA[i] = lA + sbase; dB[i] = lB + sbase;
  }
  for (int k0 = 0; k0 < LATENT; k0 += 64) {
#pragma unroll
    for (int i = 0; i < 4; i++) gload16(Ab + soff[i] + k0, dA[i]);
#pragma unroll
    for (int i = 0; i < 4; i++) gload16(Bb + soff[i] + k0, dB[i]);
    __syncthreads();
#pragma unroll
    for (int ks = 0; ks < 2; ks++) {
      bf16x8 af[4], bvv[4];
      int sw = ((ks * 4 + qq) ^ (l16 & 7)) * 8;
#pragma unroll
      for (int f = 0; f < 4; f++) {
        af[f]  = *(const bf16x8*)(lA + (wm + f * 16 + l16) * 64 + sw);
        bvv[f] = *(const bf16x8*)(lB + (wn + f * 16 + l16) * 64 + sw);
      }
#pragma unroll
      for (int fm = 0; fm < 4; fm++)
#pragma unroll
        for (int fn = 0; fn < 4; fn++)
          acc[fm][fn] = mfma_bf16(af[fm], bvv[fn], acc[fm][fn]);
    }
    __syncthreads();
  }

  // ---- epilogues (verified)
  if (!isSup && cb < 4) {
    int colb = cb * 128 + wn + l16;
#pragma unroll
    for (int fn = 0; fn < 4; fn++) {
      int c = colb + fn * 16;
      if (c < 400) {
        float scv = sc[c], ccv = cc[c];
#pragma unroll
        for (int fm = 0; fm < 4; fm++)
#pragma unroll
          for (int r = 0; r < 4; r++) {
            size_t row = arow0 + wm + fm * 16 + qq * 4 + r;
            float v = acc[fm][fn][r] + xxb[row] * scv + ccv;
            size_t idx = (c < 200) ? (SUP_OFF + row * NOUT + c)
                                   : (row * NOUT + (c - 200));
            out[idx] = v;
          }
      }
    }
  } else {
    const float* xxsrc = (isSup ? xxsup : xxb) + arow0;
    const float* yyb   = yys + (isSup ? cb * 128 : (cb - 4) * 128);
    unsigned int* rmptr   = (isSup ? rowmin + BATCH : rowmin) + arow0;
    unsigned int* colatom = isSup ? (colsup + cb * 128) : (colx + (cb - 4) * 128);
    int colo = wn + l16;
    float yv[4];
#pragma unroll
    for (int fn = 0; fn < 4; fn++) yv[fn] = yyb[colo + fn * 16];
    float cmin[4] = {3.4e38f, 3.4e38f, 3.4e38f, 3.4e38f};
#pragma unroll
    for (int fm = 0; fm < 4; fm++) {
#pragma unroll
      for (int r = 0; r < 4; r++) {
        float xvv = xxsrc[wm + fm * 16 + qq * 4 + r];
        float rmin = 3.4e38f;
#pragma unroll
        for (int fn = 0; fn < 4; fn++) {
          float d = xvv - 2.0f * acc[fm][fn][r] + yv[fn];
          rmin = fminf(rmin, d);
          cmin[fn] = fminf(cmin[fn], d);
        }
        for (int off = 1; off < 16; off <<= 1) rmin = fminf(rmin, __shfl_xor(rmin, off));
        if (l16 == 0) atomicMin(rmptr + wm + fm * 16 + qq * 4 + r, __float_as_uint(rmin));
      }
    }
#pragma unroll
    for (int fn = 0; fn < 4; fn++) {
      float v = cmin[fn];
      v = fminf(v, __shfl_xor(v, 16));
      v = fminf(v, __shfl_xor(v, 32));
      if (qq == 0) atomicMin(colatom + colo + fn * 16, __float_as_uint(v));
    }
  }
}

// =============== parallel means of mins -> r1,r2,r3,r4 (atomicAdd partials)
__global__ __launch_bounds__(256) void k_final2(const unsigned int* __restrict__ rowmin,
    const unsigned int* __restrict__ colx, const unsigned int* __restrict__ colsup,
    float* __restrict__ out4) {
  int bx = blockIdx.x, t = threadIdx.x;
  const unsigned int* src; int n; float scale; int slot;
  if (bx < 32)      { src = rowmin + bx * 1024; n = 1024; scale = 1.f / BATCH; slot = 1; }
  else if (bx == 32){ src = colx;               n = 1024; scale = 1.f / NSUB;  slot = 0; }
  else if (bx == 33){ src = rowmin + BATCH;     n = 256;  scale = 1.f / NSUP;  slot = 2; }
  else              { src = colsup;             n = 1024; scale = 1.f / NSUB;  slot = 3; }
  float s = 0.f;
  for (int i = t; i < n; i += 256) s += __uint_as_float(src[i]);
  __shared__ float red[4];
  for (int off = 32; off; off >>= 1) s += __shfl_down(s, off);
  if ((t & 63) == 0) red[t >> 6] = s;
  __syncthreads();
  if (t == 0) atomicAdd(out4 + slot, (red[0] + red[1] + red[2] + red[3]) * scale);
}

extern "C" void kernel_launch(void* const* d_in, const int* in_sizes, int n_in,
                              void* d_out, int out_size, void* d_ws, size_t ws_size,
                              hipStream_t stream) {
  const float* x   = (const float*)d_in[0];
  const float* sup = (const float*)d_in[1];
  const float* sub = (const float*)d_in[2];
  const float* W1  = (const float*)d_in[3];
  const float* b1  = (const float*)d_in[4];
  const float* W2  = (const float*)d_in[5];
  const float* b2  = (const float*)d_in[6];
  float* out = (float*)d_out;

  char* p = (char*)d_ws;
  u16* Bext  = (u16*)p;            p += (size_t)(512 + NSUB) * LATENT * 2; // Mt(512) ++ subs(1024)
  u16* Mt    = Bext;
  u16* subs  = Bext + (size_t)512 * LATENT;
  u16* sups  = (u16*)p;            p += (size_t)NSUP * LATENT * 2;
  float* xxsup = (float*)p;        p += NSUP * 4;
  float* yys   = (float*)p;        p += NSUB * 4;
  float* sc    = (float*)p;        p += 512 * 4;
  float* cc    = (float*)p;        p += 512 * 4;
  unsigned int* rowmin = (unsigned int*)p; p += (size_t)(BATCH + NSUP) * 4;
  unsigned int* colx   = (unsigned int*)p; p += (size_t)NSUB * 4;
  unsigned int* colsup = (unsigned int*)p; p += (size_t)NSUB * 4;
  u16* xbuf    = (u16*)p;          p += (size_t)BATCH * LATENT * 2;   // 33.5 MB
  float* xxb   = (float*)p;        p += (size_t)BATCH * 4;

  float* out4 = out + 2 * SUP_OFF;

  hipLaunchKernelGGL(k_setup2, dim3(8906), dim3(256), 0, stream,
                     x, sup, sub, W1, W2, xbuf, xxb, sups, subs, xxsup, yys,
                     Mt, rowmin, out4);
  hipLaunchKernelGGL(k_w, dim3(100), dim3(256), 0, stream,
                     W1, b1, W2, b2, xxsup, yys, sc, cc);
  hipLaunchKernelGGL(k_main, dim3(3088), dim3(256), 0, stream,
                     xbuf, Bext, xxb, xxsup, yys, sc, cc, sups, subs,
                     out, rowmin, colx, colsup);
  hipLaunchKernelGGL(k_final2, dim3(35), dim3(256), 0, stream, rowmin, colx, colsup, out4);
}

// Round 14
// 248.545 us; speedup vs baseline: 1.2094x; 1.0536x over previous
//
#include <hip/hip_runtime.h>
#include <stdint.h>

#define BATCH   32768
#define NSUP    256
#define NSUB    1024
#define LATENT  512
#define NOUT    200
#define SUP_OFF ((size_t)BATCH * NOUT)  // sup_out offset in d_out

typedef unsigned short u16;
typedef __attribute__((ext_vector_type(8))) __bf16 bf16x8;
typedef __attribute__((ext_vector_type(4))) float  floatx4;

typedef const __attribute__((address_space(1))) void* gptr_t;
typedef __attribute__((address_space(3))) void* sptr_t;

__device__ __forceinline__ void gload16(const void* g, void* l) {
  __builtin_amdgcn_global_load_lds((gptr_t)g, (sptr_t)l, 16, 0, 0);
}

__device__ __forceinline__ floatx4 mfma_bf16(bf16x8 a, bf16x8 b, floatx4 c) {
  return __builtin_amdgcn_mfma_f32_16x16x32_bf16(a, b, c, 0, 0, 0);
}

__device__ __forceinline__ u16 f2bf(float f) {
  unsigned int u = __float_as_uint(f);
  u += 0x7FFFu + ((u >> 16) & 1u);   // RNE; inputs finite
  return (u16)(u >> 16);
}

// =============== k_prep: Mt + slice-sc/cc + conversions + inits, ONE launch.
// bx [0,256)    : Mt[o][k] = -2 sum_j W[o,j] P[j,k]  (verified s_load variant)
// bx [256,276)  : sc/cc SLICES: block owns 64 rows of one family, norms them into
//                 256B LDS (no cross-block dep, no redundancy), then per-output
//                 partial dot -> atomicAdd into memset-zeroed sc/cc. Bias added by
//                 the j0==0 slice of each family.
// bx [276,8788) : conversions, contiguous rows (verified)
// bx [8788,8925): init 35072 min-slots; bx 8925: zero out4
__global__ __launch_bounds__(256) void k_prep(const float* __restrict__ x,
    const float* __restrict__ sup, const float* __restrict__ sub,
    const float* __restrict__ W1, const float* __restrict__ b1,
    const float* __restrict__ W2, const float* __restrict__ b2,
    u16* __restrict__ xb, float* __restrict__ xxb,
    u16* __restrict__ sups, u16* __restrict__ subs,
    float* __restrict__ xxsup, float* __restrict__ yys,
    u16* __restrict__ Mt, float* __restrict__ sc, float* __restrict__ cc,
    unsigned int* __restrict__ minbuf, float* __restrict__ out4) {
  __shared__ float nl[64];    // 256 B, used only by slice blocks
  int bx = blockIdx.x, t = threadIdx.x;
  int wave = t >> 6, lane = t & 63;

  if (bx < 256) {
    // ---- Mt build (verified): W reads wave-uniform -> s_load; P coalesced
    int og = bx >> 2, kq = bx & 3;
    int o0 = og * 8;
    int kk = t & 127, oh = t >> 7;
    int k  = kq * 128 + kk;
    if (o0 >= 400) {
#pragma unroll
      for (int oo = 0; oo < 4; oo++) Mt[(size_t)(o0 + oh * 4 + oo) * LATENT + k] = 0;
      return;
    }
    const float* P; const float* W; int n, ow;
    if (o0 < 200) { P = sup; W = W1; n = NSUP;  ow = o0; }
    else          { P = sub; W = W2; n = NSUB;  ow = o0 - 200; }
    const float* W0 = W + (size_t)(ow + oh * 4) * n;
    float a[4] = {};
    for (int j = 0; j < n; j += 16) {
      float pv[16];
#pragma unroll
      for (int u = 0; u < 16; u++) pv[u] = P[(size_t)(j + u) * LATENT + k];
#pragma unroll
      for (int oo = 0; oo < 4; oo++) {
        const float* Wr = W0 + (size_t)oo * n + j;   // wave-uniform -> s_load
#pragma unroll
        for (int u = 0; u < 16; u++) a[oo] += pv[u] * Wr[u];
      }
    }
#pragma unroll
    for (int oo = 0; oo < 4; oo++)
      Mt[(size_t)(o0 + oh * 4 + oo) * LATENT + k] = f2bf(-2.f * a[oo]);
    return;
  }
  if (bx < 276) {
    // ---- sc/cc slice: 4 sup slices (sb 0..3) + 16 sub slices (sb 4..19)
    int sb = bx - 256;
    int famSub = (sb >= 4);
    int j0   = famSub ? (sb - 4) * 64 : sb * 64;
    int n    = famSub ? NSUB : NSUP;
    int oB   = famSub ? 200 : 0;
    const float* P    = famSub ? sub : sup;
    const float* W    = famSub ? W2 : W1;
    const float* bias = famSub ? b2 : b1;
    // norms of rows j0..j0+63 (16 rows per wave)
    for (int i = wave; i < 64; i += 4) {
      const float* s = P + (size_t)(j0 + i) * LATENT + lane * 8;
      float4 v0 = ((const float4*)s)[0];
      float4 v1 = ((const float4*)s)[1];
      float ss = v0.x*v0.x + v0.y*v0.y + v0.z*v0.z + v0.w*v0.w
               + v1.x*v1.x + v1.y*v1.y + v1.z*v1.z + v1.w*v1.w;
      for (int off = 32; off; off >>= 1) ss += __shfl_down(ss, off);
      if (lane == 0) nl[i] = ss;
    }
    __syncthreads();
    if (t < 200) {
      const float* Wr = W + (size_t)t * n + j0;
      float ws = 0.f, c = 0.f;
#pragma unroll 8
      for (int u = 0; u < 64; u++) { float w = Wr[u]; ws += w; c += w * nl[u]; }
      if (j0 == 0) c += bias[t];
      atomicAdd(sc + oB + t, ws);
      atomicAdd(cc + oB + t, c);
    }
    return;
  }
  if (bx >= 8788) {
    if (bx == 8925) { if (t < 4) out4[t] = 0.f; return; }
    int i = (bx - 8788) * 256 + t;
    if (i < BATCH + NSUP + 2 * NSUB) minbuf[i] = 0x7F800000u;
    return;
  }
  // ---- conversions + row norms (verified, contiguous)
  int row  = (bx - 276) * 4 + wave;
  const float* src; u16* dst; float* nrm;
  if (row < BATCH) {
    src = x + (size_t)row * LATENT; dst = xb + (size_t)row * LATENT; nrm = xxb + row;
  } else if (row < BATCH + NSUP) {
    int r = row - BATCH;
    src = sup + (size_t)r * LATENT; dst = sups + (size_t)r * LATENT; nrm = xxsup + r;
  } else {
    int r = row - BATCH - NSUP;
    src = sub + (size_t)r * LATENT; dst = subs + (size_t)r * LATENT; nrm = yys + r;
  }
  const float* s = src + lane * 8;
  float4 v0 = ((const float4*)s)[0];
  float4 v1 = ((const float4*)s)[1];
  float ss = v0.x*v0.x + v0.y*v0.y + v0.z*v0.z + v0.w*v0.w
           + v1.x*v1.x + v1.y*v1.y + v1.z*v1.z + v1.w*v1.w;
  uint4 o;
  o.x = (unsigned)f2bf(v0.x) | ((unsigned)f2bf(v0.y) << 16);
  o.y = (unsigned)f2bf(v0.z) | ((unsigned)f2bf(v0.w) << 16);
  o.z = (unsigned)f2bf(v1.x) | ((unsigned)f2bf(v1.y) << 16);
  o.w = (unsigned)f2bf(v1.z) | ((unsigned)f2bf(v1.w) << 16);
  *((uint4*)(dst + lane * 8)) = o;
  for (int off = 32; off; off >>= 1) ss += __shfl_down(ss, off);
  if (lane == 0) *nrm = ss;
}

// =============== main GEMM kernel: verified 128x128 K-loop (84 µs, 0 conflicts).
// bx [0,16): sup x sub tiles first; bx [16,3088): x-GEMM tiles, XCD-swizzled.
__global__ __launch_bounds__(256, 4) void k_main(const u16* __restrict__ xb,
    const u16* __restrict__ Bext, const float* __restrict__ xxb,
    const float* __restrict__ xxsup, const float* __restrict__ yys,
    const float* __restrict__ sc, const float* __restrict__ cc,
    const u16* __restrict__ sups, const u16* __restrict__ subs,
    float* __restrict__ out, unsigned int* __restrict__ rowmin,
    unsigned int* __restrict__ colx, unsigned int* __restrict__ colsup) {
  __shared__ __align__(16) u16 lA[128 * 64];
  __shared__ __align__(16) u16 lB[128 * 64];
  int bx = blockIdx.x, t = threadIdx.x, wave = t >> 6, lane = t & 63;
  int l16 = lane & 15, qq = lane >> 4;
  int wm = (wave >> 1) * 64, wn = (wave & 1) * 64;

  const u16* Ab; const u16* Bb;
  int cb, isSup; size_t arow0;
  if (bx < 16) {
    cb = bx & 7; arow0 = (size_t)(bx >> 3) * 128; isSup = 1;
    Ab = sups + arow0 * LATENT; Bb = subs + (size_t)cb * 128 * LATENT;
  } else {
    int g = bx - 16;
    int xcd = g & 7, local = g >> 3;
    int rowt = xcd * 32 + local / 12;
    cb = local % 12;
    arow0 = (size_t)rowt * 128; isSup = 0;
    Ab = xb + arow0 * LATENT; Bb = Bext + (size_t)cb * 128 * LATENT;
  }

  floatx4 acc[4][4] = {};
  int sq = (lane & 7) ^ (lane >> 3);
  int soff[4]; u16 *dA[4], *dB[4];
#pragma unroll
  for (int i = 0; i < 4; i++) {
    int s = i * 256 + t;
    soff[i] = (s >> 3) * LATENT + sq * 8;
    int sbase = (i * 256 + wave * 64) * 8;
    dA[i] = lA + sbase; dB[i] = lB + sbase;
  }
  for (int k0 = 0; k0 < LATENT; k0 += 64) {
#pragma unroll
    for (int i = 0; i < 4; i++) gload16(Ab + soff[i] + k0, dA[i]);
#pragma unroll
    for (int i = 0; i < 4; i++) gload16(Bb + soff[i] + k0, dB[i]);
    __syncthreads();
#pragma unroll
    for (int ks = 0; ks < 2; ks++) {
      bf16x8 af[4], bvv[4];
      int sw = ((ks * 4 + qq) ^ (l16 & 7)) * 8;
#pragma unroll
      for (int f = 0; f < 4; f++) {
        af[f]  = *(const bf16x8*)(lA + (wm + f * 16 + l16) * 64 + sw);
        bvv[f] = *(const bf16x8*)(lB + (wn + f * 16 + l16) * 64 + sw);
      }
#pragma unroll
      for (int fm = 0; fm < 4; fm++)
#pragma unroll
        for (int fn = 0; fn < 4; fn++)
          acc[fm][fn] = mfma_bf16(af[fm], bvv[fn], acc[fm][fn]);
    }
    __syncthreads();
  }

  if (!isSup && cb < 4) {
    int colb = cb * 128 + wn + l16;
#pragma unroll
    for (int fn = 0; fn < 4; fn++) {
      int c = colb + fn * 16;
      if (c < 400) {
        float scv = sc[c], ccv = cc[c];
#pragma unroll
        for (int fm = 0; fm < 4; fm++)
#pragma unroll
          for (int r = 0; r < 4; r++) {
            size_t row = arow0 + wm + fm * 16 + qq * 4 + r;
            float v = acc[fm][fn][r] + xxb[row] * scv + ccv;
            size_t idx = (c < 200) ? (SUP_OFF + row * NOUT + c)
                                   : (row * NOUT + (c - 200));
            out[idx] = v;
          }
      }
    }
  } else {
    const float* xxsrc = (isSup ? xxsup : xxb) + arow0;
    const float* yyb   = yys + (isSup ? cb * 128 : (cb - 4) * 128);
    unsigned int* rmptr   = (isSup ? rowmin + BATCH : rowmin) + arow0;
    unsigned int* colatom = isSup ? (colsup + cb * 128) : (colx + (cb - 4) * 128);
    int colo = wn + l16;
    float yv[4];
#pragma unroll
    for (int fn = 0; fn < 4; fn++) yv[fn] = yyb[colo + fn * 16];
    float cmin[4] = {3.4e38f, 3.4e38f, 3.4e38f, 3.4e38f};
#pragma unroll
    for (int fm = 0; fm < 4; fm++) {
#pragma unroll
      for (int r = 0; r < 4; r++) {
        float xvv = xxsrc[wm + fm * 16 + qq * 4 + r];
        float rmin = 3.4e38f;
#pragma unroll
        for (int fn = 0; fn < 4; fn++) {
          float d = xvv - 2.0f * acc[fm][fn][r] + yv[fn];
          rmin = fminf(rmin, d);
          cmin[fn] = fminf(cmin[fn], d);
        }
        for (int off = 1; off < 16; off <<= 1) rmin = fminf(rmin, __shfl_xor(rmin, off));
        if (l16 == 0) atomicMin(rmptr + wm + fm * 16 + qq * 4 + r, __float_as_uint(rmin));
      }
    }
#pragma unroll
    for (int fn = 0; fn < 4; fn++) {
      float v = cmin[fn];
      v = fminf(v, __shfl_xor(v, 16));
      v = fminf(v, __shfl_xor(v, 32));
      if (qq == 0) atomicMin(colatom + colo + fn * 16, __float_as_uint(v));
    }
  }
}

// =============== parallel means of mins -> r1,r2,r3,r4 (atomicAdd partials)
__global__ __launch_bounds__(256) void k_final2(const unsigned int* __restrict__ rowmin,
    const unsigned int* __restrict__ colx, const unsigned int* __restrict__ colsup,
    float* __restrict__ out4) {
  int bx = blockIdx.x, t = threadIdx.x;
  const unsigned int* src; int n; float scale; int slot;
  if (bx < 32)      { src = rowmin + bx * 1024; n = 1024; scale = 1.f / BATCH; slot = 1; }
  else if (bx == 32){ src = colx;               n = 1024; scale = 1.f / NSUB;  slot = 0; }
  else if (bx == 33){ src = rowmin + BATCH;     n = 256;  scale = 1.f / NSUP;  slot = 2; }
  else              { src = colsup;             n = 1024; scale = 1.f / NSUB;  slot = 3; }
  float s = 0.f;
  for (int i = t; i < n; i += 256) s += __uint_as_float(src[i]);
  __shared__ float red[4];
  for (int off = 32; off; off >>= 1) s += __shfl_down(s, off);
  if ((t & 63) == 0) red[t >> 6] = s;
  __syncthreads();
  if (t == 0) atomicAdd(out4 + slot, (red[0] + red[1] + red[2] + red[3]) * scale);
}

extern "C" void kernel_launch(void* const* d_in, const int* in_sizes, int n_in,
                              void* d_out, int out_size, void* d_ws, size_t ws_size,
                              hipStream_t stream) {
  const float* x   = (const float*)d_in[0];
  const float* sup = (const float*)d_in[1];
  const float* sub = (const float*)d_in[2];
  const float* W1  = (const float*)d_in[3];
  const float* b1  = (const float*)d_in[4];
  const float* W2  = (const float*)d_in[5];
  const float* b2  = (const float*)d_in[6];
  float* out = (float*)d_out;

  char* p = (char*)d_ws;
  u16* Bext  = (u16*)p;            p += (size_t)(512 + NSUB) * LATENT * 2; // Mt(512) ++ subs(1024)
  u16* Mt    = Bext;
  u16* subs  = Bext + (size_t)512 * LATENT;
  u16* sups  = (u16*)p;            p += (size_t)NSUP * LATENT * 2;
  float* xxsup = (float*)p;        p += NSUP * 4;
  float* yys   = (float*)p;        p += NSUB * 4;
  float* sc    = (float*)p;        p += 512 * 4;
  float* cc    = (float*)p;        p += 512 * 4;
  unsigned int* rowmin = (unsigned int*)p; p += (size_t)(BATCH + NSUP) * 4;
  unsigned int* colx   = (unsigned int*)p; p += (size_t)NSUB * 4;
  unsigned int* colsup = (unsigned int*)p; p += (size_t)NSUB * 4;
  u16* xbuf    = (u16*)p;          p += (size_t)BATCH * LATENT * 2;   // 33.5 MB
  float* xxb   = (float*)p;        p += (size_t)BATCH * 4;

  float* out4 = out + 2 * SUP_OFF;

  // zero sc/cc (atomicAdd targets); contiguous 4 KB
  hipMemsetAsync(sc, 0, 1024 * sizeof(float), stream);
  hipLaunchKernelGGL(k_prep, dim3(8926), dim3(256), 0, stream,
                     x, sup, sub, W1, b1, W2, b2, xbuf, xxb, sups, subs,
                     xxsup, yys, Mt, sc, cc, rowmin, out4);
  hipLaunchKernelGGL(k_main, dim3(3088), dim3(256), 0, stream,
                     xbuf, Bext, xxb, xxsup, yys, sc, cc, sups, subs,
                     out, rowmin, colx, colsup);
  hipLaunchKernelGGL(k_final2, dim3(35), dim3(256), 0, stream, rowmin, colx, colsup, out4);
}